// Round 2
// baseline (1031.024 us; speedup 1.0000x reference)
//
#include <hip/hip_runtime.h>
#include <math.h>

typedef unsigned short u16;
typedef __attribute__((ext_vector_type(8))) short short8;
typedef __attribute__((ext_vector_type(4))) float floatx4;
typedef __attribute__((ext_vector_type(4))) unsigned short ushort4v;

#define DEV static __device__ __forceinline__

DEV u16 f2b(float f) {
  unsigned u = __builtin_bit_cast(unsigned, f);
  u += 0x7fffu + ((u >> 16) & 1u);
  return (u16)(u >> 16);
}
DEV float b2f(u16 h) { return __builtin_bit_cast(float, ((unsigned)h) << 16); }

DEV void gld16(const u16* g, u16* l) {
  __builtin_amdgcn_global_load_lds((__attribute__((address_space(1))) void*)(g),
                                   (__attribute__((address_space(3))) void*)(l), 16, 0, 0);
}

// ---------------- K1: token-shift mixes -> 6 bf16 tensors ----------------
__global__ __launch_bounds__(256) void ew_mix(
    const float* __restrict__ x,
    const float* __restrict__ cr, const float* __restrict__ ck,
    const float* __restrict__ cv, const float* __restrict__ cw,
    const float* __restrict__ ca, const float* __restrict__ cg,
    u16* __restrict__ oxr, u16* __restrict__ oxk, u16* __restrict__ oxv,
    u16* __restrict__ oxw, u16* __restrict__ oxa, u16* __restrict__ oxg)
{
  const long idx = (long)blockIdx.x * 256 + threadIdx.x;
  const long row = idx >> 9;
  const int c4 = (int)(idx & 511) << 2;
  const long off = (row << 11) + c4;
  const float4 xc = *(const float4*)(x + off);
  float4 xp = make_float4(0.f, 0.f, 0.f, 0.f);
  if ((row & 4095) != 0) xp = *(const float4*)(x + off - 2048);
  const float xx0 = xp.x - xc.x, xx1 = xp.y - xc.y, xx2 = xp.z - xc.z, xx3 = xp.w - xc.w;
#define EMIT(cp, op) { const float4 cf = *(const float4*)(cp + c4);            \
    ushort4v o = { f2b(xc.x + xx0*cf.x), f2b(xc.y + xx1*cf.y),                 \
                   f2b(xc.z + xx2*cf.z), f2b(xc.w + xx3*cf.w) };               \
    *(ushort4v*)(op + off) = o; }
  EMIT(cr, oxr); EMIT(ck, oxk); EMIT(cv, oxv);
  EMIT(cw, oxw); EMIT(ca, oxa); EMIT(cg, oxg);
#undef EMIT
}

// ---------------- K2: cast 4 big square weights f32 -> bf16 ----------------
__global__ __launch_bounds__(256) void cast_w4(
    const float* __restrict__ s0, const float* __restrict__ s1,
    const float* __restrict__ s2, const float* __restrict__ s3,
    u16* __restrict__ d0, u16* __restrict__ d1, u16* __restrict__ d2, u16* __restrict__ d3)
{
  const float* s; u16* d;
  switch (blockIdx.y) {
    case 0: s = s0; d = d0; break;
    case 1: s = s1; d = d1; break;
    case 2: s = s2; d = d2; break;
    default: s = s3; d = d3; break;
  }
  const long i = ((long)blockIdx.x * 256 + threadIdx.x) * 8;
  const float4 a = *(const float4*)(s + i);
  const float4 b = *(const float4*)(s + i + 4);
  ushort4v lo = { f2b(a.x), f2b(a.y), f2b(a.z), f2b(a.w) };
  ushort4v hi = { f2b(b.x), f2b(b.y), f2b(b.z), f2b(b.w) };
  *(ushort4v*)(d + i) = lo;
  *(ushort4v*)(d + i + 4) = hi;
}

// ---------------- K3: transpose (+zero-pad) LoRA weights -> bf16 [N][K] ----------------
struct TJobs {
  const float* src[8]; u16* dst[8];
  int src_k[8], src_n[8], dst_n[8], dst_k[8];
};
__global__ __launch_bounds__(256) void transpose_small(TJobs j)
{
  const int w = blockIdx.y;
  const long idx = (long)blockIdx.x * 256 + threadIdx.x;
  const long total = (long)j.dst_n[w] * j.dst_k[w];
  if (idx >= total) return;
  const int dk = j.dst_k[w];
  const int n = (int)(idx / dk), k = (int)(idx % dk);
  float v = 0.f;
  if (k < j.src_k[w] && n < j.src_n[w]) v = j.src[w][(long)k * j.src_n[w] + n];
  j.dst[w][idx] = f2b(v);
}

// ---------------- GEMM 128x128 (m97 structure), job-table, runtime epilogue op ----------------
// ops: 1=bf16  2=tanh->bf16  3=sig->bf16  4=w-f32(+bias)  5=sig-f32(+bias)  6=sig-bf16(+bias)
struct J128 { const u16* A; const u16* B; void* C; const float* bias; int N, K, lda, op, b0; };
struct J128v { J128 j[4]; };

__global__ __launch_bounds__(256, 2) void gemm128(J128v jv)
{
  __shared__ __align__(16) u16 sA[128 * 64];
  __shared__ __align__(16) u16 sB[128 * 64];
  const int bid = blockIdx.x;
  int jid = 0;
#pragma unroll
  for (int q = 1; q < 4; ++q) if (bid >= jv.j[q].b0) jid = q;
  const J128 J = jv.j[jid];
  const int lb = bid - J.b0;
  const int tid = threadIdx.x;
  const int wave = tid >> 6, lane = tid & 63;
  const int lrow = lane & 15, lkg = lane >> 4;
  const int wm = wave >> 1, wn = wave & 1;
  const int nbn = J.N >> 7;
  const int bm = lb / nbn, bn = lb % nbn;

  const u16* Abase = J.A + (long)bm * 128 * J.lda;
  const u16* Bbase = J.B + (long)bn * 128 * J.K;

  floatx4 acc[4][4];
#pragma unroll
  for (int i = 0; i < 4; ++i)
#pragma unroll
    for (int jq = 0; jq < 4; ++jq) acc[i][jq] = (floatx4)0.f;

  const int nK = J.K >> 6;
  for (int kt = 0; kt < nK; ++kt) {
    const int k0 = kt << 6;
    __syncthreads();
#pragma unroll
    for (int i = 0; i < 4; ++i) {
      const int c = i * 256 + tid;
      const int row = c >> 3;
      const int sch = (c & 7) ^ (row & 7);
      const long goffA = (long)row * J.lda + k0 + sch * 8;
      const long goffB = (long)row * J.K + k0 + sch * 8;
      const int lbase = (i * 256 + wave * 64) * 8;
      gld16(Abase + goffA, &sA[lbase]);
      gld16(Bbase + goffB, &sB[lbase]);
    }
    asm volatile("s_waitcnt vmcnt(0)" ::: "memory");
    __syncthreads();
#pragma unroll
    for (int ks = 0; ks < 2; ++ks) {
      short8 af[4], bfr[4];
#pragma unroll
      for (int mi = 0; mi < 4; ++mi) {
        const int row = wm * 64 + mi * 16 + lrow;
        const int ch = (ks * 4 + lkg) ^ (row & 7);
        af[mi] = *(const short8*)&sA[row * 64 + ch * 8];
      }
#pragma unroll
      for (int ni = 0; ni < 4; ++ni) {
        const int row = wn * 64 + ni * 16 + lrow;
        const int ch = (ks * 4 + lkg) ^ (row & 7);
        bfr[ni] = *(const short8*)&sB[row * 64 + ch * 8];
      }
#pragma unroll
      for (int mi = 0; mi < 4; ++mi)
#pragma unroll
        for (int ni = 0; ni < 4; ++ni)
          acc[mi][ni] = __builtin_amdgcn_mfma_f32_16x16x32_bf16(af[mi], bfr[ni], acc[mi][ni], 0, 0, 0);
    }
  }

  const int row0 = bm * 128 + wm * 64 + lkg * 4;
  const int col0 = bn * 128 + wn * 64 + lrow;
  const int op = J.op;
#pragma unroll
  for (int mi = 0; mi < 4; ++mi) {
#pragma unroll
    for (int ni = 0; ni < 4; ++ni) {
      const int col = col0 + ni * 16;
#pragma unroll
      for (int r = 0; r < 4; ++r) {
        const long o = (long)(row0 + mi * 16 + r) * J.N + col;
        const float v = acc[mi][ni][r];
        if (op == 1) ((u16*)J.C)[o] = f2b(v);
        else if (op == 2) ((u16*)J.C)[o] = f2b(tanhf(v));
        else if (op == 3) ((u16*)J.C)[o] = f2b(1.f / (1.f + expf(-v)));
        else if (op == 4) {
          const float zz = -(v + J.bias[col]);
          const float sp = fmaxf(zz, 0.f) + log1pf(expf(-fabsf(zz)));
          ((float*)J.C)[o] = -sp - 0.5f;
        } else if (op == 5) {
          ((float*)J.C)[o] = 1.f / (1.f + expf(-(v + J.bias[col])));
        } else {  // 6
          ((u16*)J.C)[o] = f2b(1.f / (1.f + expf(-(v + J.bias[col]))));
        }
      }
    }
  }
}

// ---------------- GEMM 256x256 deep-pipelined (8-phase, counted vmcnt) ----------------
// Fixed M=8192, N=2048, K=2048. C[M,N] = A[M,K] @ B[N,K]^T, bf16 in.
// LDS: 8 slots x 16KB; unit s=4t+j: j0=A kc0, j1=B kc0, j2=A kc1, j3=B kc1 of K-tile t.
// Stage lead 6 (slot s&7); vmcnt(4) at each tile's last phase; raw s_barrier only.
// Ledger (verified): unit s overwrites s-8 whose last read is >=1 barrier before
// the staging phase; vmcnt(4) at phase 4t+3 lands all units of tile t+1.
struct G256 { const u16* A[2]; const u16* B[2]; void* C[2]; };

template<int OP>  // 0=f32 out, 1=bf16 out
__global__ __launch_bounds__(512, 2) void gemm256(G256 g)
{
  __shared__ __align__(16) u16 lds[8 * 8192];
  const int tid = threadIdx.x;
  const int wave = tid >> 6, lane = tid & 63;
  const int lrow = lane & 15, lq = lane >> 4;
  const int wm = wave >> 2, wn = wave & 3;
  const int job = blockIdx.x >> 8;
  const int lb = blockIdx.x & 255;
  const int bm = lb >> 3, bn = lb & 7;

  const u16* __restrict__ Ab = g.A[job] + (long)bm * 256 * 2048;
  const u16* __restrict__ Bb = g.B[job] + (long)bn * 256 * 2048;

  // staging per-thread precompute (2 loads per unit)
  int srco[2], dsto[2];
#pragma unroll
  for (int l = 0; l < 2; ++l) {
    const int c = l * 512 + tid;
    const int row = c >> 2, q = c & 3;
    const int qs = q ^ ((row >> 1) & 3);
    srco[l] = row * 2048 + qs * 8;
    dsto[l] = (l * 512 + wave * 64) * 8;
  }
  // fragment read offsets (swizzled), per qm/mi and ni
  int offA[2][4], offB[4];
#pragma unroll
  for (int qm = 0; qm < 2; ++qm)
#pragma unroll
    for (int mi = 0; mi < 4; ++mi) {
      const int r = wm * 128 + qm * 64 + mi * 16 + lrow;
      offA[qm][mi] = r * 32 + (lq ^ ((r >> 1) & 3)) * 8;
    }
#pragma unroll
  for (int ni = 0; ni < 4; ++ni) {
    const int r = wn * 64 + ni * 16 + lrow;
    offB[ni] = r * 32 + (lq ^ ((r >> 1) & 3)) * 8;
  }

  floatx4 acc[8][4];
#pragma unroll
  for (int i = 0; i < 8; ++i)
#pragma unroll
    for (int jq = 0; jq < 4; ++jq) acc[i][jq] = (floatx4)0.f;

#define STAGE(sU, slot) {                                                  \
    const int t_ = (sU) >> 2, j_ = (sU) & 3;                               \
    const u16* base_ = (j_ & 1) ? Bb : Ab;                                 \
    const int kofs_ = t_ * 64 + ((j_ & 2) ? 32 : 0);                       \
    gld16(base_ + srco[0] + kofs_, &lds[(slot) * 8192 + dsto[0]]);         \
    gld16(base_ + srco[1] + kofs_, &lds[(slot) * 8192 + dsto[1]]);         \
  }

  // prologue: units 0..5; land 0..3
#pragma unroll
  for (int s = 0; s < 6; ++s) STAGE(s, s);
  asm volatile("s_waitcnt vmcnt(4)" ::: "memory");
  asm volatile("s_barrier" ::: "memory");

  const int nT = 32;                 // K/64
  for (int te = 0; te < nT; te += 2) {
#pragma unroll
    for (int ph = 0; ph < 8; ++ph) {  // two tiles: te (ph 0-3), te+1 (ph 4-7)
      const int ks = (ph >> 1) & 1, qm = ph & 1;
      const int slotA = (ph & 4) ? (4 + 2 * ks) : (2 * ks);
      const int slotB = slotA + 1;
      short8 af[4], bf[4];
#pragma unroll
      for (int mi = 0; mi < 4; ++mi)
        af[mi] = *(const short8*)&lds[slotA * 8192 + offA[qm][mi]];
#pragma unroll
      for (int ni = 0; ni < 4; ++ni)
        bf[ni] = *(const short8*)&lds[slotB * 8192 + offB[ni]];
      const int sU = 4 * te + 6 + ph;
      if (sU < 4 * nT) { STAGE(sU, (6 + ph) & 7); }
      if ((ph & 3) == 3) asm volatile("s_waitcnt vmcnt(4)" ::: "memory");
      asm volatile("s_barrier" ::: "memory");
      __builtin_amdgcn_s_setprio(1);
      const int am = qm * 4;
#pragma unroll
      for (int mi = 0; mi < 4; ++mi)
#pragma unroll
        for (int ni = 0; ni < 4; ++ni)
          acc[am + mi][ni] = __builtin_amdgcn_mfma_f32_16x16x32_bf16(af[mi], bf[ni], acc[am + mi][ni], 0, 0, 0);
      __builtin_amdgcn_s_setprio(0);
      asm volatile("s_barrier" ::: "memory");
    }
  }
#undef STAGE

  // epilogue: row = lq*4 + reg (within frag), col = lrow
  const long row0 = (long)bm * 256 + wm * 128 + lq * 4;
  const int col0 = bn * 256 + wn * 64 + lrow;
#pragma unroll
  for (int mi = 0; mi < 8; ++mi) {
#pragma unroll
    for (int ni = 0; ni < 4; ++ni) {
      const int col = col0 + ni * 16;
#pragma unroll
      for (int r = 0; r < 4; ++r) {
        const long o = (row0 + mi * 16 + r) * 2048 + col;
        const float v = acc[mi][ni][r];
        if constexpr (OP == 0) ((float*)g.C[job])[o] = v;
        else ((u16*)g.C[job])[o] = f2b(v);
      }
    }
  }
}

// ---------------- K6: per-head fused epilogue ----------------
DEV float wsum64(float v) {
  v += __shfl_xor(v, 1);  v += __shfl_xor(v, 2);  v += __shfl_xor(v, 4);
  v += __shfl_xor(v, 8);  v += __shfl_xor(v, 16); v += __shfl_xor(v, 32);
  return v;
}

__global__ __launch_bounds__(256) void ew_head(
    const u16* __restrict__ r16, const u16* __restrict__ k16,
    float* __restrict__ kkout,
    const float* __restrict__ abuf,
    const u16* __restrict__ v0buf, const u16* __restrict__ vsbuf,
    const u16* __restrict__ gbuf,
    const float* __restrict__ y, const float* __restrict__ vfirst,
    const float* __restrict__ kkc, const float* __restrict__ kac,
    const float* __restrict__ rk, const float* __restrict__ lng,
    const float* __restrict__ lnb, u16* __restrict__ z)
{
  const int tid = threadIdx.x;
  const int wave = tid >> 6, lane = tid & 63;
  const long gh = (long)blockIdx.x * 4 + wave;
  const long m = gh >> 5;
  const int h = (int)(gh & 31);
  const int c = h * 64 + lane;
  const long off = (m << 11) + c;

  const float k0 = b2f(k16[off]);
  const float av = abuf[off];
  const float kf = k0 * (1.f + (av - 1.f) * kac[c]);
  const float kkr = k0 * kkc[c];
  const float nrm = sqrtf(wsum64(kkr * kkr));
  kkout[off] = kkr / fmaxf(nrm, 1e-12f);

  const float yv = y[off];
  const float mu = wsum64(yv) * 0.015625f;
  const float dy = yv - mu;
  const float var = wsum64(dy * dy) * 0.015625f;
  const float yn = dy * rsqrtf(var + 0.00064f) * lng[c] + lnb[c];

  const float dot = wsum64(b2f(r16[off]) * kf * rk[c]);

  const float v0v = b2f(v0buf[off]);
  const float sv = b2f(vsbuf[off]);
  const float vv = v0v + (vfirst[off] - v0v) * sv;

  const float y2 = yn + dot * vv;
  z[off] = f2b(y2 * b2f(gbuf[off]));
}

// ---------------- launch ----------------
extern "C" void kernel_launch(void* const* d_in, const int* in_sizes, int n_in,
                              void* d_out, int out_size, void* d_ws, size_t ws_size,
                              hipStream_t stream)
{
  (void)in_sizes; (void)out_size;
  if (n_in < 29) return;
  const int Mrows = 8192;
  const long C = 2048;
  const long MB_ = (long)Mrows * C;

  const float* x   = (const float*)d_in[0];
  const float* vf  = (const float*)d_in[1];
  const float* y   = (const float*)d_in[2];
  const float* x_r = (const float*)d_in[3];
  const float* x_w = (const float*)d_in[4];
  const float* x_k = (const float*)d_in[5];
  const float* x_v = (const float*)d_in[6];
  const float* x_a = (const float*)d_in[7];
  const float* x_g = (const float*)d_in[8];
  const float* w0  = (const float*)d_in[9];
  const float* w1  = (const float*)d_in[10];
  const float* w2  = (const float*)d_in[11];
  const float* a0  = (const float*)d_in[12];
  const float* a1  = (const float*)d_in[13];
  const float* a2  = (const float*)d_in[14];
  const float* v0  = (const float*)d_in[15];
  const float* v1  = (const float*)d_in[16];
  const float* v2  = (const float*)d_in[17];
  const float* g1  = (const float*)d_in[18];
  const float* g2  = (const float*)d_in[19];
  const float* k_k = (const float*)d_in[20];
  const float* k_a = (const float*)d_in[21];
  const float* r_k = (const float*)d_in[22];
  const float* W_r = (const float*)d_in[23];
  const float* W_k = (const float*)d_in[24];
  const float* W_v = (const float*)d_in[25];
  const float* W_o = (const float*)d_in[26];
  const float* lng = (const float*)d_in[27];
  const float* lnb = (const float*)d_in[28];

  float* out_sec = (float*)d_out;
  float* w_sec   = out_sec + MB_;
  float* a_sec   = w_sec + MB_;
  float* kk_sec  = a_sec + MB_;

  // bf16 intermediates parked in dead d_out regions:
  u16* k16 = (u16*)out_sec;            // [0, MB_) u16
  u16* r16 = (u16*)out_sec + MB_;      // [MB_, 2*MB_) u16  (both dead before final GEMM)
  u16* Wr16 = (u16*)w_sec;             // weight casts, dead before stage-2 w-job writes w_sec
  u16* Wk16 = Wr16 + C * C;
  u16* Wv16 = Wk16 + C * C;

  u16* p = (u16*)d_ws;
  u16* xr = p;            p += MB_;
  u16* xk = p;            p += MB_;   // later z
  u16* xv = p;            p += MB_;
  u16* xw = p;            p += MB_;   // later vs
  u16* xa = p;            p += MB_;   // later g
  u16* xg = p;            p += MB_;
  u16* Wo16 = p;          p += C * C;
  u16* w1T = p;           p += 128 * C;
  u16* a1T = p;           p += 128 * C;
  u16* v1T = p;           p += 128 * C;   // rows 64.. zero
  u16* g1T = p;           p += 256 * C;   // rows 224.. zero
  u16* w2T = p;           p += C * 128;
  u16* a2T = p;           p += C * 128;
  u16* v2T = p;           p += C * 128;   // cols 64.. zero
  u16* g2T = p;           p += C * 256;
  u16* hw  = p;           p += (long)Mrows * 128;
  u16* ha  = p;           p += (long)Mrows * 128;
  u16* hv  = p;           p += (long)Mrows * 128;
  u16* hg  = p;           p += (long)Mrows * 256;
  const size_t need = (size_t)((char*)p - (char*)d_ws);
  if (ws_size < need) return;

  u16* v0buf = xr;   // written by launch 5b, AFTER 5a's r-job read xr
  u16* zbuf  = xk;
  u16* vsbuf = xw;
  u16* gbuf  = xa;

  // 1: mixes
  ew_mix<<<16384, 256, 0, stream>>>(x, x_r, x_k, x_v, x_w, x_a, x_g,
                                    xr, xk, xv, xw, xa, xg);
  // 2: big weight casts
  cast_w4<<<dim3(2048, 4), 256, 0, stream>>>(W_r, W_k, W_v, W_o, Wr16, Wk16, Wv16, Wo16);
  // 3: LoRA weight transposes (+zero pad)
  TJobs tj;
  {
    const float* s_[8] = { w1, a1, v1, g1, w2, a2, v2, g2 };
    u16* d_[8]         = { w1T, a1T, v1T, g1T, w2T, a2T, v2T, g2T };
    const int sk_[8]   = { 2048, 2048, 2048, 2048, 128, 128, 64, 224 };
    const int sn_[8]   = { 128, 128, 64, 224, 2048, 2048, 2048, 2048 };
    const int dn_[8]   = { 128, 128, 128, 256, 2048, 2048, 2048, 2048 };
    const int dk_[8]   = { 2048, 2048, 2048, 2048, 128, 128, 128, 256 };
    for (int i = 0; i < 8; ++i) {
      tj.src[i] = s_[i]; tj.dst[i] = d_[i];
      tj.src_k[i] = sk_[i]; tj.src_n[i] = sn_[i];
      tj.dst_n[i] = dn_[i]; tj.dst_k[i] = dk_[i];
    }
  }
  transpose_small<<<dim3(2048, 8), 256, 0, stream>>>(tj);

  const int IMAX = 0x7fffffff;
  // 4: LoRA stage-1 (one launch, 320 blocks)
  {
    J128v jv;
    jv.j[0] = { xw, w1T, hw, nullptr, 128, 2048, 2048, 2, 0 };
    jv.j[1] = { xa, a1T, ha, nullptr, 128, 2048, 2048, 1, 64 };
    jv.j[2] = { xv, v1T, hv, nullptr, 128, 2048, 2048, 1, 128 };
    jv.j[3] = { xg, g1T, hg, nullptr, 256, 2048, 2048, 3, 192 };
    gemm128<<<320, 256, 0, stream>>>(jv);
  }
  // 5a: r,k projections (256^2 pipelined)
  {
    G256 g; g.A[0] = xr; g.B[0] = Wr16; g.C[0] = r16;
            g.A[1] = xk; g.B[1] = Wk16; g.C[1] = k16;
    gemm256<1><<<512, 512, 0, stream>>>(g);
  }
  // 5b: v projection (output aliases xr -> must follow 5a)
  {
    G256 g; g.A[0] = xv; g.B[0] = Wv16; g.C[0] = v0buf;
            g.A[1] = xv; g.B[1] = Wv16; g.C[1] = v0buf;
    gemm256<1><<<256, 512, 0, stream>>>(g);
  }
  // 6: LoRA stage-2 (one launch, 4096 blocks; w-job overwrites weight casts -> after 5)
  {
    J128v jv;
    jv.j[0] = { hw, w2T, w_sec, w0, 2048, 128, 128, 4, 0 };
    jv.j[1] = { ha, a2T, a_sec, a0, 2048, 128, 128, 5, 1024 };
    jv.j[2] = { hv, v2T, vsbuf, v0, 2048, 128, 128, 6, 2048 };
    jv.j[3] = { hg, g2T, gbuf, nullptr, 2048, 256, 256, 1, 3072 };
    (void)IMAX;
    gemm128<<<4096, 256, 0, stream>>>(jv);
  }
  // 7: fused per-head epilogue -> kk + z
  ew_head<<<65536, 256, 0, stream>>>(r16, k16, kk_sec, a_sec, v0buf, vsbuf, gbuf,
                                     y, vf, k_k, k_a, r_k, lng, lnb, zbuf);
  // 8: final projection (overwrites out_sec; r16/k16 dead)
  {
    G256 g; g.A[0] = zbuf; g.B[0] = Wo16; g.C[0] = out_sec;
            g.A[1] = zbuf; g.B[1] = Wo16; g.C[1] = out_sec;
    gemm256<0><<<256, 512, 0, stream>>>(g);
  }
}